// Round 7
// baseline (1014.041 us; speedup 1.0000x reference)
//
#include <hip/hip_runtime.h>
#include <math.h>

#define NB 8192
#define NIN 64
#define NOUT 128
#define NHID 32
#define NEXO 3
#define EXROWS 192
#define NTGT 2

typedef float f32x4 __attribute__((ext_vector_type(4)));
typedef short bf16x8 __attribute__((ext_vector_type(8)));

__device__ __forceinline__ float sigmoidf(float x) {
    return 1.0f / (1.0f + __expf(-x));
}

__device__ __forceinline__ unsigned short f2bf(float x) {   // RNE float->bf16
    unsigned int u = __float_as_uint(x);
    unsigned int r = u + 0x7fffu + ((u >> 16) & 1u);
    return (unsigned short)(r >> 16);
}

// DPP-based cross-lane add (VALU pipe).
// CTRL: 0xB1 = quad_perm[1,0,3,2] (xor1), 0x4E = quad_perm[2,3,0,1] (xor2),
//       0x141 = row_half_mirror (xor7), 0x128 = row_ror:8 (xor8 within 16).
template<int CTRL>
__device__ __forceinline__ float dpp_add(float x) {
    int p = __builtin_amdgcn_update_dpp(0, __float_as_int(x), CTRL, 0xf, 0xf, true);
    return x + __int_as_float(p);
}
__device__ __forceinline__ float swz_add_xor16(float x) {   // ds_swizzle xor16
    int p = __builtin_amdgcn_ds_swizzle(__float_as_int(x), 0x401f);
    return x + __int_as_float(p);
}

// -------------------------------------------------------------------------
// Kernel A (MFMA): E[b,i,o] = b1+b3 + out1_exog + out2_exog, written to out.
// (unchanged from round 6)
// -------------------------------------------------------------------------
__global__ __launch_bounds__(256, 4) void narx_exog_kernel(
    const float* __restrict__ exog,
    const float* __restrict__ W1, const float* __restrict__ b1,
    const float* __restrict__ W2, const float* __restrict__ b2,
    const float* __restrict__ W3, const float* __restrict__ b3,
    float* __restrict__ E)
{
    __shared__ __align__(16) float exs[NEXO][EXROWS];
    __shared__ __align__(16) unsigned short exrep[NEXO * 8][200];
    __shared__ __align__(16) unsigned short w2bf[NEXO * 32][72];
    __shared__ __align__(16) float2 w1e2[NEXO][NIN];
    __shared__ __align__(16) float b2l[96];
    __shared__ __align__(16) float w3l[2][96];

    const int tid = threadIdx.x;
    const int b = blockIdx.x;
    const float* exb = exog + (size_t)b * (EXROWS * NEXO);

    for (int idx = tid; idx < EXROWS * NEXO; idx += 256) {
        int t = idx / 3;
        int e = idx - t * 3;
        exs[e][t] = exb[idx];
    }
    for (int idx = tid; idx < 6144; idx += 256) {
        int e = idx >> 11;
        int rem = idx & 2047;
        int u = rem >> 6, t = rem & 63;
        w2bf[e * 32 + u][t] = f2bf(W2[(size_t)(64 + e * 32 + u) * NIN + t]);
    }
    for (int idx = tid; idx < 192; idx += 256) {
        int e = idx >> 6, t = idx & 63;
        w1e2[e][t] = make_float2(W1[t * 5 + 2 + e], W1[320 + t * 5 + 2 + e]);
    }
    if (tid < 96)  b2l[tid] = b2[64 + tid];
    for (int idx = tid; idx < 192; idx += 256) {
        int o = idx / 96, u = idx - o * 96;
        w3l[o][u] = W3[o * 160 + 64 + u];
    }
    __syncthreads();

    for (int idx = tid; idx < NEXO * 8 * 192; idx += 256) {
        int e = idx / 1536;
        int rem = idx - e * 1536;
        int r = rem / 192;
        int q = rem - r * 192;
        float v = (q + r < 192) ? exs[e][q + r] : 0.f;
        exrep[e * 8 + r][q] = f2bf(v);
    }
    __syncthreads();

    const int wv = tid >> 6;
    const int l  = tid & 63;
    const int iw = wv * 32;
    const int lg = l >> 4;
    const int col = l & 15;

    float acc0[2] = {0.f, 0.f};
    float acc1[2] = {0.f, 0.f};

    #pragma unroll 1
    for (int e = 0; e < NEXO; ++e) {
        f32x4 b2v[2], w30v[2], w31v[2];
        #pragma unroll
        for (int mt = 0; mt < 2; ++mt) {
            b2v[mt]  = *(const f32x4*)&b2l[e * 32 + mt * 16 + lg * 4];
            w30v[mt] = *(const f32x4*)&w3l[0][e * 32 + mt * 16 + lg * 4];
            w31v[mt] = *(const f32x4*)&w3l[1][e * 32 + mt * 16 + lg * 4];
        }

        f32x4 cacc[2][2];
        #pragma unroll
        for (int mt = 0; mt < 2; ++mt)
            #pragma unroll
            for (int nt = 0; nt < 2; ++nt)
                cacc[mt][nt] = b2v[mt];

        #pragma unroll
        for (int kt = 0; kt < 2; ++kt) {
            bf16x8 af[2], bfr[2];
            #pragma unroll
            for (int mt = 0; mt < 2; ++mt)
                af[mt] = *(const bf16x8*)&w2bf[e * 32 + mt * 16 + col][kt * 32 + lg * 8];
            #pragma unroll
            for (int nt = 0; nt < 2; ++nt)
                bfr[nt] = *(const bf16x8*)&exrep[e * 8 + (l & 7)]
                              [iw + nt * 16 + kt * 32 + lg * 8 + ((l >> 3) & 1) * 8];
            #pragma unroll
            for (int mt = 0; mt < 2; ++mt)
                #pragma unroll
                for (int nt = 0; nt < 2; ++nt)
                    cacc[mt][nt] = __builtin_amdgcn_mfma_f32_16x16x32_bf16(
                        af[mt], bfr[nt], cacc[mt][nt], 0, 0, 0);
        }

        #pragma unroll
        for (int mt = 0; mt < 2; ++mt)
            #pragma unroll
            for (int nt = 0; nt < 2; ++nt) {
                #pragma unroll
                for (int r = 0; r < 4; ++r) {
                    float sg = sigmoidf(cacc[mt][nt][r]);
                    acc0[nt] += w30v[mt][r] * sg;
                    acc1[nt] += w31v[mt][r] * sg;
                }
            }

        const float* exs_e = &exs[e][0];
        #pragma unroll
        for (int dt = 0; dt < 16; ++dt) {
            float2 wv2 = w1e2[e][lg * 16 + dt];
            float x0 = exs_e[iw + l + dt];
            float x1 = exs_e[iw + 16 + l + dt];
            acc0[0] += wv2.x * x0;
            acc1[0] += wv2.y * x0;
            acc0[1] += wv2.x * x1;
            acc1[1] += wv2.y * x1;
        }
    }

    #pragma unroll
    for (int nt = 0; nt < 2; ++nt) {
        acc0[nt] += __shfl_xor(acc0[nt], 16, 64);
        acc0[nt] += __shfl_xor(acc0[nt], 32, 64);
        acc1[nt] += __shfl_xor(acc1[nt], 16, 64);
        acc1[nt] += __shfl_xor(acc1[nt], 32, 64);
    }
    if (lg == 0) {
        const float bias0 = b1[0] + b3[0];
        const float bias1 = b1[1] + b3[1];
        #pragma unroll
        for (int nt = 0; nt < 2; ++nt) {
            int i = iw + nt * 16 + col;
            *(float2*)&E[(size_t)b * (NOUT * NTGT) + i * 2] =
                make_float2(acc0[nt] + bias0, acc1[nt] + bias1);
        }
    }
}

// -------------------------------------------------------------------------
// Kernel B: recurrence. 4 batches per 256-thread block, one per wave.
// __launch_bounds__(256,4): VGPR cap 128 so w2[64]+P[8]+ev8[8] live in
// arch VGPRs (no AGPR round-trips / remat). Reduce: permlane32_swap
// (VALU) cross-half fold + ds_swizzle xor16 + DPP {8,7,2,1}.
// E stored series-transposed (e2s[w][s][i]) -> aligned broadcast b128
// prefetch. Own/other output weights pre-selected outside the loop.
// -------------------------------------------------------------------------
#define CH 8

__global__ __launch_bounds__(256, 4) void narx_recur_kernel(
    const float* __restrict__ target,
    const float* __restrict__ W1,
    const float* __restrict__ W2, const float* __restrict__ b2,
    const float* __restrict__ W3,
    float* __restrict__ out)
{
    __shared__ __align__(16) float y[4][NTGT][200];
    __shared__ __align__(16) float e2s[4][NTGT][NOUT];

    const int tid = threadIdx.x;
    const int w = tid >> 6;
    const int l = tid & 63;
    const int s = l >> 5;
    const int h = l & 31;
    const int b = blockIdx.x * 4 + w;

    {
        float2 tv = *(const float2*)&target[(size_t)b * (NIN * NTGT) + l * 2];
        y[w][0][l] = tv.x;
        y[w][1][l] = tv.y;
    }
    {
        float4 ev = *(const float4*)&out[(size_t)b * (NOUT * NTGT) + l * 4];
        e2s[w][0][2 * l]     = ev.x;
        e2s[w][1][2 * l]     = ev.y;
        e2s[w][0][2 * l + 1] = ev.z;
        e2s[w][1][2 * l + 1] = ev.w;
    }
    __syncthreads();

    float w2[NIN];
    const float* wr = W2 + (s * NHID + h) * NIN;
    #pragma unroll
    for (int t4 = 0; t4 < 16; ++t4) {
        float4 wv = *(const float4*)(wr + t4 * 4);
        w2[t4*4+0] = wv.x; w2[t4*4+1] = wv.y; w2[t4*4+2] = wv.z; w2[t4*4+3] = wv.w;
    }
    const float bb = b2[s * NHID + h];
    // own = this half's output (o = s); oth = the other output.
    const float w3own = W3[s * 160 + s * NHID + h];
    const float w3oth = W3[(1 - s) * 160 + s * NHID + h];
    float wo1[2], wo2[2];
    #pragma unroll
    for (int dt = 0; dt < 2; ++dt) {
        wo1[dt] = W1[s * 320 + (2 * h + dt) * 5 + s];
        wo2[dt] = W1[(1 - s) * 320 + (2 * h + dt) * 5 + s];
    }

    float* yw = &y[w][s][0];
    const float* e2p = &e2s[w][s][0];

    #pragma unroll 1
    for (int c = 0; c < NOUT / CH; ++c) {
        const int i0 = c * CH;

        // ---- prefetch E for this chunk: 2 aligned broadcast b128 ----
        float4 ea = *(const float4*)&e2p[i0];
        float4 eb = *(const float4*)&e2p[i0 + 4];
        float ev8[CH] = { ea.x, ea.y, ea.z, ea.w, eb.x, eb.y, eb.z, eb.w };

        // ---- stream precompute: P[ci] = bb + sum over known window ----
        float P[CH];
        #pragma unroll
        for (int j = 0; j < CH; ++j) P[j] = bb;
        float ylast = 0.f;
        #pragma unroll
        for (int kq = 0; kq < 16; ++kq) {
            float4 yv = *(const float4*)&yw[i0 + kq * 4];
            #pragma unroll
            for (int d = 0; d < 4; ++d) {
                const int k = kq * 4 + d;
                const float yk = (d == 0) ? yv.x : (d == 1) ? yv.y : (d == 2) ? yv.z : yv.w;
                #pragma unroll
                for (int ci = 0; ci < CH; ++ci) {
                    if (ci <= k) P[ci] += w2[k - ci] * yk;
                }
                if (k == 63) ylast = yk;
            }
        }

        // ---- 8 sequential steps ----
        float predprev = ylast;
        #pragma unroll
        for (int ci = 0; ci < CH; ++ci) {
            const int i = i0 + ci;
            const float y1a = yw[i + 2 * h];
            const float y1b = yw[i + 2 * h + 1];

            const float sg = sigmoidf(P[ci]);
            float va = w3own * sg + wo1[0] * y1a + wo1[1] * y1b;  // own output
            float vb = w3oth * sg + wo2[0] * y1a + wo2[1] * y1b;  // other output

            // cross-half fold on the VALU: other half's "other-output" partial
            auto r = __builtin_amdgcn_permlane32_swap(
                __float_as_uint(vb), __float_as_uint(vb), false, false);
            float cc = va + (s ? __uint_as_float(r[0]) : __uint_as_float(r[1]));
            cc = swz_add_xor16(cc);       // xor 16 (LDS swizzle)
            cc = dpp_add<0x128>(cc);      // xor 8  (row_ror:8)
            cc = dpp_add<0x141>(cc);      // xor 7  (row_half_mirror)
            cc = dpp_add<0x4E>(cc);       // xor 2
            cc = dpp_add<0xB1>(cc);       // xor 1

            const float pred = cc + ev8[ci] + predprev;
            #pragma unroll
            for (int cj = ci + 1; cj < CH; ++cj)
                P[cj] += w2[64 - (cj - ci)] * pred;
            if (h == 0) yw[i + 64] = pred;
            predprev = pred;
        }
    }

    {
        float4 ov;
        ov.x = y[w][0][64 + 2 * l];
        ov.y = y[w][1][64 + 2 * l];
        ov.z = y[w][0][64 + 2 * l + 1];
        ov.w = y[w][1][64 + 2 * l + 1];
        *(float4*)&out[(size_t)b * (NOUT * NTGT) + l * 4] = ov;
    }
}

extern "C" void kernel_launch(void* const* d_in, const int* in_sizes, int n_in,
                              void* d_out, int out_size, void* d_ws, size_t ws_size,
                              hipStream_t stream) {
    (void)in_sizes; (void)n_in; (void)out_size; (void)d_ws; (void)ws_size;
    const float* target = (const float*)d_in[0];
    const float* exog   = (const float*)d_in[1];
    const float* W1     = (const float*)d_in[2];
    const float* b1     = (const float*)d_in[3];
    const float* W2     = (const float*)d_in[4];
    const float* b2     = (const float*)d_in[5];
    const float* W3     = (const float*)d_in[6];
    const float* b3     = (const float*)d_in[7];
    float* out = (float*)d_out;

    hipLaunchKernelGGL(narx_exog_kernel, dim3(NB), dim3(256), 0, stream,
                       exog, W1, b1, W2, b2, W3, b3, out);
    hipLaunchKernelGGL(narx_recur_kernel, dim3(NB / 4), dim3(256), 0, stream,
                       target, W1, W2, b2, W3, out);
}

// Round 8
// 251.920 us; speedup vs baseline: 4.0252x; 4.0252x over previous
//
#include <hip/hip_runtime.h>
#include <math.h>

#define NB 8192
#define NIN 64
#define NOUT 128
#define NHID 32
#define NEXO 3
#define EXROWS 192
#define NTGT 2

typedef float f32x4 __attribute__((ext_vector_type(4)));
typedef short bf16x8 __attribute__((ext_vector_type(8)));

__device__ __forceinline__ float sigmoidf(float x) {
    return 1.0f / (1.0f + __expf(-x));
}

__device__ __forceinline__ unsigned short f2bf(float x) {   // RNE float->bf16
    unsigned int u = __float_as_uint(x);
    unsigned int r = u + 0x7fffu + ((u >> 16) & 1u);
    return (unsigned short)(r >> 16);
}

// DPP-based cross-lane add (VALU pipe).
// CTRL: 0xB1 = quad_perm[1,0,3,2] (xor1), 0x4E = quad_perm[2,3,0,1] (xor2),
//       0x141 = row_half_mirror (xor7), 0x128 = row_ror:8 (xor8 within 16).
template<int CTRL>
__device__ __forceinline__ float dpp_add(float x) {
    int p = __builtin_amdgcn_update_dpp(0, __float_as_int(x), CTRL, 0xf, 0xf, true);
    return x + __int_as_float(p);
}
__device__ __forceinline__ float swz_add_xor16(float x) {   // ds_swizzle xor16
    int p = __builtin_amdgcn_ds_swizzle(__float_as_int(x), 0x401f);
    return x + __int_as_float(p);
}

// -------------------------------------------------------------------------
// Kernel A (MFMA): E[b,i,o] = b1+b3 + out1_exog + out2_exog, written to out.
// (unchanged from round 6)
// -------------------------------------------------------------------------
__global__ __launch_bounds__(256, 4) void narx_exog_kernel(
    const float* __restrict__ exog,
    const float* __restrict__ W1, const float* __restrict__ b1,
    const float* __restrict__ W2, const float* __restrict__ b2,
    const float* __restrict__ W3, const float* __restrict__ b3,
    float* __restrict__ E)
{
    __shared__ __align__(16) float exs[NEXO][EXROWS];
    __shared__ __align__(16) unsigned short exrep[NEXO * 8][200];
    __shared__ __align__(16) unsigned short w2bf[NEXO * 32][72];
    __shared__ __align__(16) float2 w1e2[NEXO][NIN];
    __shared__ __align__(16) float b2l[96];
    __shared__ __align__(16) float w3l[2][96];

    const int tid = threadIdx.x;
    const int b = blockIdx.x;
    const float* exb = exog + (size_t)b * (EXROWS * NEXO);

    for (int idx = tid; idx < EXROWS * NEXO; idx += 256) {
        int t = idx / 3;
        int e = idx - t * 3;
        exs[e][t] = exb[idx];
    }
    for (int idx = tid; idx < 6144; idx += 256) {
        int e = idx >> 11;
        int rem = idx & 2047;
        int u = rem >> 6, t = rem & 63;
        w2bf[e * 32 + u][t] = f2bf(W2[(size_t)(64 + e * 32 + u) * NIN + t]);
    }
    for (int idx = tid; idx < 192; idx += 256) {
        int e = idx >> 6, t = idx & 63;
        w1e2[e][t] = make_float2(W1[t * 5 + 2 + e], W1[320 + t * 5 + 2 + e]);
    }
    if (tid < 96)  b2l[tid] = b2[64 + tid];
    for (int idx = tid; idx < 192; idx += 256) {
        int o = idx / 96, u = idx - o * 96;
        w3l[o][u] = W3[o * 160 + 64 + u];
    }
    __syncthreads();

    for (int idx = tid; idx < NEXO * 8 * 192; idx += 256) {
        int e = idx / 1536;
        int rem = idx - e * 1536;
        int r = rem / 192;
        int q = rem - r * 192;
        float v = (q + r < 192) ? exs[e][q + r] : 0.f;
        exrep[e * 8 + r][q] = f2bf(v);
    }
    __syncthreads();

    const int wv = tid >> 6;
    const int l  = tid & 63;
    const int iw = wv * 32;
    const int lg = l >> 4;
    const int col = l & 15;

    float acc0[2] = {0.f, 0.f};
    float acc1[2] = {0.f, 0.f};

    #pragma unroll 1
    for (int e = 0; e < NEXO; ++e) {
        f32x4 b2v[2], w30v[2], w31v[2];
        #pragma unroll
        for (int mt = 0; mt < 2; ++mt) {
            b2v[mt]  = *(const f32x4*)&b2l[e * 32 + mt * 16 + lg * 4];
            w30v[mt] = *(const f32x4*)&w3l[0][e * 32 + mt * 16 + lg * 4];
            w31v[mt] = *(const f32x4*)&w3l[1][e * 32 + mt * 16 + lg * 4];
        }

        f32x4 cacc[2][2];
        #pragma unroll
        for (int mt = 0; mt < 2; ++mt)
            #pragma unroll
            for (int nt = 0; nt < 2; ++nt)
                cacc[mt][nt] = b2v[mt];

        #pragma unroll
        for (int kt = 0; kt < 2; ++kt) {
            bf16x8 af[2], bfr[2];
            #pragma unroll
            for (int mt = 0; mt < 2; ++mt)
                af[mt] = *(const bf16x8*)&w2bf[e * 32 + mt * 16 + col][kt * 32 + lg * 8];
            #pragma unroll
            for (int nt = 0; nt < 2; ++nt)
                bfr[nt] = *(const bf16x8*)&exrep[e * 8 + (l & 7)]
                              [iw + nt * 16 + kt * 32 + lg * 8 + ((l >> 3) & 1) * 8];
            #pragma unroll
            for (int mt = 0; mt < 2; ++mt)
                #pragma unroll
                for (int nt = 0; nt < 2; ++nt)
                    cacc[mt][nt] = __builtin_amdgcn_mfma_f32_16x16x32_bf16(
                        af[mt], bfr[nt], cacc[mt][nt], 0, 0, 0);
        }

        #pragma unroll
        for (int mt = 0; mt < 2; ++mt)
            #pragma unroll
            for (int nt = 0; nt < 2; ++nt) {
                #pragma unroll
                for (int r = 0; r < 4; ++r) {
                    float sg = sigmoidf(cacc[mt][nt][r]);
                    acc0[nt] += w30v[mt][r] * sg;
                    acc1[nt] += w31v[mt][r] * sg;
                }
            }

        const float* exs_e = &exs[e][0];
        #pragma unroll
        for (int dt = 0; dt < 16; ++dt) {
            float2 wv2 = w1e2[e][lg * 16 + dt];
            float x0 = exs_e[iw + l + dt];
            float x1 = exs_e[iw + 16 + l + dt];
            acc0[0] += wv2.x * x0;
            acc1[0] += wv2.y * x0;
            acc0[1] += wv2.x * x1;
            acc1[1] += wv2.y * x1;
        }
    }

    #pragma unroll
    for (int nt = 0; nt < 2; ++nt) {
        acc0[nt] += __shfl_xor(acc0[nt], 16, 64);
        acc0[nt] += __shfl_xor(acc0[nt], 32, 64);
        acc1[nt] += __shfl_xor(acc1[nt], 16, 64);
        acc1[nt] += __shfl_xor(acc1[nt], 32, 64);
    }
    if (lg == 0) {
        const float bias0 = b1[0] + b3[0];
        const float bias1 = b1[1] + b3[1];
        #pragma unroll
        for (int nt = 0; nt < 2; ++nt) {
            int i = iw + nt * 16 + col;
            *(float2*)&E[(size_t)b * (NOUT * NTGT) + i * 2] =
                make_float2(acc0[nt] + bias0, acc1[nt] + bias1);
        }
    }
}

// -------------------------------------------------------------------------
// Kernel B: recurrence. 4 batches per 256-thread block, one per wave.
// __launch_bounds__(256,2): empirically hipcc's VGPR budget is ~256/w, so
// w=2 -> cap 128; the ~110-reg live set (w2[64]+P[8]+temps) fits in arch
// VGPRs -> no AGPR round-trips (r6) and no scratch (r7).
// Reduce: permlane32_swap (VALU) + ds_swizzle xor16 + DPP {8,7,2,1}.
// -------------------------------------------------------------------------
#define CH 8

__global__ __launch_bounds__(256, 2) void narx_recur_kernel(
    const float* __restrict__ target,
    const float* __restrict__ W1,
    const float* __restrict__ W2, const float* __restrict__ b2,
    const float* __restrict__ W3,
    float* __restrict__ out)
{
    __shared__ __align__(16) float y[4][NTGT][200];
    __shared__ __align__(16) float e2s[4][NTGT][NOUT];

    const int tid = threadIdx.x;
    const int w = tid >> 6;
    const int l = tid & 63;
    const int s = l >> 5;
    const int h = l & 31;
    const int b = blockIdx.x * 4 + w;

    {
        float2 tv = *(const float2*)&target[(size_t)b * (NIN * NTGT) + l * 2];
        y[w][0][l] = tv.x;
        y[w][1][l] = tv.y;
    }
    {
        float4 ev = *(const float4*)&out[(size_t)b * (NOUT * NTGT) + l * 4];
        e2s[w][0][2 * l]     = ev.x;
        e2s[w][1][2 * l]     = ev.y;
        e2s[w][0][2 * l + 1] = ev.z;
        e2s[w][1][2 * l + 1] = ev.w;
    }
    __syncthreads();

    float w2[NIN];
    const float* wr = W2 + (s * NHID + h) * NIN;
    #pragma unroll
    for (int t4 = 0; t4 < 16; ++t4) {
        float4 wv = *(const float4*)(wr + t4 * 4);
        w2[t4*4+0] = wv.x; w2[t4*4+1] = wv.y; w2[t4*4+2] = wv.z; w2[t4*4+3] = wv.w;
    }
    const float bb = b2[s * NHID + h];
    // own = this half's output (o = s); oth = the other output.
    const float w3own = W3[s * 160 + s * NHID + h];
    const float w3oth = W3[(1 - s) * 160 + s * NHID + h];
    float wo1[2], wo2[2];
    #pragma unroll
    for (int dt = 0; dt < 2; ++dt) {
        wo1[dt] = W1[s * 320 + (2 * h + dt) * 5 + s];
        wo2[dt] = W1[(1 - s) * 320 + (2 * h + dt) * 5 + s];
    }

    float* yw = &y[w][s][0];
    const float* e2p = &e2s[w][s][0];

    #pragma unroll 1
    for (int c = 0; c < NOUT / CH; ++c) {
        const int i0 = c * CH;

        // ---- stream precompute: P[ci] = bb + sum over known window ----
        float P[CH];
        #pragma unroll
        for (int j = 0; j < CH; ++j) P[j] = bb;
        float ylast = 0.f;
        #pragma unroll
        for (int kq = 0; kq < 16; ++kq) {
            float4 yv = *(const float4*)&yw[i0 + kq * 4];
            #pragma unroll
            for (int d = 0; d < 4; ++d) {
                const int k = kq * 4 + d;
                const float yk = (d == 0) ? yv.x : (d == 1) ? yv.y : (d == 2) ? yv.z : yv.w;
                #pragma unroll
                for (int ci = 0; ci < CH; ++ci) {
                    if (ci <= k) P[ci] += w2[k - ci] * yk;
                }
                if (k == 63) ylast = yk;
            }
        }

        // ---- prefetch E for this chunk AFTER precompute (lower peak regs) ----
        float4 ea = *(const float4*)&e2p[i0];
        float4 eb = *(const float4*)&e2p[i0 + 4];
        float ev8[CH] = { ea.x, ea.y, ea.z, ea.w, eb.x, eb.y, eb.z, eb.w };

        // ---- 8 sequential steps ----
        float predprev = ylast;
        #pragma unroll
        for (int ci = 0; ci < CH; ++ci) {
            const int i = i0 + ci;
            const float y1a = yw[i + 2 * h];
            const float y1b = yw[i + 2 * h + 1];

            const float sg = sigmoidf(P[ci]);
            float va = w3own * sg + wo1[0] * y1a + wo1[1] * y1b;  // own output
            float vb = w3oth * sg + wo2[0] * y1a + wo2[1] * y1b;  // other output

            // cross-half fold on the VALU: other half's "other-output" partial
            auto r = __builtin_amdgcn_permlane32_swap(
                __float_as_uint(vb), __float_as_uint(vb), false, false);
            float cc = va + (s ? __uint_as_float(r[0]) : __uint_as_float(r[1]));
            cc = swz_add_xor16(cc);       // xor 16 (LDS swizzle)
            cc = dpp_add<0x128>(cc);      // xor 8  (row_ror:8)
            cc = dpp_add<0x141>(cc);      // xor 7  (row_half_mirror)
            cc = dpp_add<0x4E>(cc);       // xor 2
            cc = dpp_add<0xB1>(cc);       // xor 1

            const float pred = cc + ev8[ci] + predprev;
            #pragma unroll
            for (int cj = ci + 1; cj < CH; ++cj)
                P[cj] += w2[64 - (cj - ci)] * pred;
            if (h == 0) yw[i + 64] = pred;
            predprev = pred;
        }
    }

    {
        float4 ov;
        ov.x = y[w][0][64 + 2 * l];
        ov.y = y[w][1][64 + 2 * l];
        ov.z = y[w][0][64 + 2 * l + 1];
        ov.w = y[w][1][64 + 2 * l + 1];
        *(float4*)&out[(size_t)b * (NOUT * NTGT) + l * 4] = ov;
    }
}

extern "C" void kernel_launch(void* const* d_in, const int* in_sizes, int n_in,
                              void* d_out, int out_size, void* d_ws, size_t ws_size,
                              hipStream_t stream) {
    (void)in_sizes; (void)n_in; (void)out_size; (void)d_ws; (void)ws_size;
    const float* target = (const float*)d_in[0];
    const float* exog   = (const float*)d_in[1];
    const float* W1     = (const float*)d_in[2];
    const float* b1     = (const float*)d_in[3];
    const float* W2     = (const float*)d_in[4];
    const float* b2     = (const float*)d_in[5];
    const float* W3     = (const float*)d_in[6];
    const float* b3     = (const float*)d_in[7];
    float* out = (float*)d_out;

    hipLaunchKernelGGL(narx_exog_kernel, dim3(NB), dim3(256), 0, stream,
                       exog, W1, b1, W2, b2, W3, b3, out);
    hipLaunchKernelGGL(narx_recur_kernel, dim3(NB / 4), dim3(256), 0, stream,
                       target, W1, W2, b2, W3, out);
}